// Round 1
// 6152.719 us; speedup vs baseline: 2.7514x; 2.7514x over previous
//
#include <hip/hip_runtime.h>
#include <cstdint>
#include <cstddef>

// ---------------------------------------------------------------------------
// 2-layer GRU imputation RNN, B=256, T=256, D_IN=128, D_H=512.
// R2: batch rows are independent => all staged data flows stay inside one
// bb-group of 16 WGs. Replace 256-WG grid barriers (whose __threadfence()
// pair emits buffer_wbl2/buffer_inv sc1 = full L2 writeback+invalidate, 768x)
// with per-group 16-WG barriers + MALL-coherent (sc0 sc1) staged load/stores.
// L2 is never flushed -> weights stay hot. H32/H132 are WG-private -> LDS.
// ---------------------------------------------------------------------------

#define BB  256
#define TT  256
#define DIN 128
#define DH  512

typedef __attribute__((ext_vector_type(8))) short short8;   // 8 x bf16
typedef __attribute__((ext_vector_type(4))) float f32x4;
typedef unsigned short u16;
typedef unsigned long long u64;

// ws layout (float units)
#define OFF_BAR   0                               // [16] group counters, 64B apart
#define OFF_HBF   256                             // [256][512] bf16 (carried h)
#define OFF_H1BF  (OFF_HBF + BB*DH/2)             // [256][512] bf16 (layer-0 out)
#define OFF_IMPBF (OFF_H1BF + BB*DH/2)            // [256][128] bf16
#define OFF_GH0   (OFF_IMPBF + BB*DIN/2)          // [3][256][512] f32 (incl. b_hh0)
#define OFF_WOUT  (OFF_GH0 + 3*BB*DH)             // bf16 weights below
#define OFF_WHH0  (OFF_WOUT + (DIN*DH)/2)
#define OFF_WIH0  (OFF_WHH0 + (3*DH*DH)/2)
#define OFF_WIH1  (OFF_WIH0 + (3*DH*DIN)/2)
#define OFF_WHH1  (OFF_WIH1 + (3*DH*DH)/2)
#define WS_FLOATS (OFF_WHH1 + (3*DH*DH)/2)        // ~1.85M floats ~ 7.4 MB

__device__ __forceinline__ float sigm(float x)   { return 1.0f / (1.0f + __expf(-x)); }
__device__ __forceinline__ float tanh_f(float x) { return 2.0f / (1.0f + __expf(-2.0f * x)) - 1.0f; }

__device__ __forceinline__ u16 f2bf(float x) {            // RNE f32->bf16
    unsigned u = __builtin_bit_cast(unsigned, x);
    u += 0x7fffu + ((u >> 16) & 1u);
    return (u16)(u >> 16);
}

// ---- MALL-coherent staged accesses (bypass L1+L2, XCD-agnostic) ------------
__device__ __forceinline__ u64 ld_u64_sc(const u16* p) {
    return __hip_atomic_load((const u64*)p, __ATOMIC_RELAXED, __HIP_MEMORY_SCOPE_AGENT);
}
__device__ __forceinline__ float ld_f32_sc(const float* p) {
    return __hip_atomic_load(p, __ATOMIC_RELAXED, __HIP_MEMORY_SCOPE_AGENT);
}
__device__ __forceinline__ void st_f32_sc(float* p, float v) {
    __hip_atomic_store(p, v, __ATOMIC_RELAXED, __HIP_MEMORY_SCOPE_AGENT);
}
__device__ __forceinline__ void st_u16_sc(u16* p, unsigned v) {
    // 16-bit atomic store would legalize to a CAS loop; raw sc0 sc1 store is
    // write-through to MALL. Untracked vmcnt only strengthens compiler waits.
    asm volatile("global_store_short %0, %1, off sc0 sc1" :: "v"(p), "v"(v) : "memory");
}

// 16-WG group barrier. Release: every wave drains its own stores (sc1 stores
// are write-through, so vmcnt(0) == data at MALL; no wbl2 needed). Acquire:
// consumers read with sc1, so no buffer_inv needed either.
__device__ __forceinline__ void group_bar(unsigned* bar, unsigned target) {
    asm volatile("s_waitcnt vmcnt(0)" ::: "memory");
    __syncthreads();
    if (threadIdx.x == 0) {
        __hip_atomic_fetch_add(bar, 1u, __ATOMIC_RELAXED, __HIP_MEMORY_SCOPE_AGENT);
        while (__hip_atomic_load(bar, __ATOMIC_RELAXED, __HIP_MEMORY_SCOPE_AGENT) < target) {
            __builtin_amdgcn_s_sleep(1);
        }
    }
    __syncthreads();
}

// fp32 -> bf16 weight conversion (runs once per call, before the RNN kernel)
__global__ void prep_kernel(const float* __restrict__ Wout, const float* __restrict__ Whh0,
                            const float* __restrict__ Wih0, const float* __restrict__ Wih1,
                            const float* __restrict__ Whh1, float* __restrict__ ws) {
    u16* dOut = (u16*)(ws + OFF_WOUT);
    u16* dHH0 = (u16*)(ws + OFF_WHH0);
    u16* dIH0 = (u16*)(ws + OFF_WIH0);
    u16* dIH1 = (u16*)(ws + OFF_WIH1);
    u16* dHH1 = (u16*)(ws + OFF_WHH1);
    const int N0 = DIN * DH, N1 = 3 * DH * DH, N2 = 3 * DH * DIN;
    const int total = N0 + 3 * N1 + N2;
    for (int i = blockIdx.x * 256 + threadIdx.x; i < total; i += gridDim.x * 256) {
        int j = i;
        if (j < N0) { dOut[j] = f2bf(Wout[j]); continue; } j -= N0;
        if (j < N1) { dHH0[j] = f2bf(Whh0[j]); continue; } j -= N1;
        if (j < N2) { dIH0[j] = f2bf(Wih0[j]); continue; } j -= N2;
        if (j < N1) { dIH1[j] = f2bf(Wih1[j]); continue; } j -= N1;
        dHH1[j] = f2bf(Whh1[j]);
    }
}

__global__ __launch_bounds__(512) void rnn_kernel(
    const float* __restrict__ X,    const float* __restrict__ Mm,
    const float* __restrict__ bih0, const float* __restrict__ bhh0,
    const float* __restrict__ bih1, const float* __restrict__ bhh1,
    const float* __restrict__ bout,
    float* __restrict__ out, float* __restrict__ ws)
{
    __shared__ __align__(16) u16 Atile[16 * 520];    // A-tile, padded rows (16B)
    __shared__ float cplane[2][3][256];              // stage-3 combine exchange
    __shared__ float H32L[16][33];                   // carried h fp32 (WG-private cols)
    __shared__ float H132L[16][33];                  // layer-0 out fp32 (WG-private)

    float* ws_bar = ws + OFF_BAR;
    u16*   Hbf  = (u16*)(ws + OFF_HBF);
    u16*   H1bf = (u16*)(ws + OFF_H1BF);
    u16*   IMPbf= (u16*)(ws + OFF_IMPBF);
    float* GH0  = ws + OFF_GH0;
    const u16* WbOut = (const u16*)(ws + OFF_WOUT);
    const u16* WbHH0 = (const u16*)(ws + OFF_WHH0);
    const u16* WbIH0 = (const u16*)(ws + OFF_WIH0);
    const u16* WbIH1 = (const u16*)(ws + OFF_WIH1);
    const u16* WbHH1 = (const u16*)(ws + OFF_WHH1);

    float* pre  = out;                               // [B][T][DIN]
    float* outc = out + BB * TT * DIN;               // [B][T][DIN]
    float* hfin = out + 2 * BB * TT * DIN;           // [B][DH]
    float* hsc  = hfin + BB * DH;                    // [B][T][DH]

    const int tid  = threadIdx.x;
    const int lane = tid & 63;
    const int v    = tid >> 6;           // wave 0..7
    const int bb   = blockIdx.x & 15;    // batch block (16 rows) == group id
    const int fg   = blockIdx.x >> 4;    // feature group
    const int m_   = lane & 15;          // A-row / B-col / C-col index
    const int q    = lane >> 4;          // quad
    const int q8   = q * 8;
    const int rowB = bb * 16 + q * 4;    // C-row batch base (+r)
    const int lrow = q * 4;              // local row base (+r)

    unsigned* bar = (unsigned*)ws_bar + bb * 16;     // 64B-spaced per-group counter
    unsigned ep = 0;

    // zero carried-h LDS (t==0 initial state)
    ((float*)H32L)[tid] = 0.f;
    if (tid < 16 * 33 - 512) ((float*)H32L)[512 + tid] = 0.f;

    for (int t = 0; t <= TT; ++t) {
        // ---------------- stage 1: A = H_prev (16 x 512) ----------------
        {
            const u16* src = Hbf + bb * 16 * DH;
            for (int ch = tid; ch < 2048; ch += 512) {
                const int r = ch >> 7, c = ch & 127;
                *(u64*)(Atile + r * 520 + c * 4) = ld_u64_sc(src + r * DH + c * 4);
            }
        }
        __syncthreads();

        const int ftile = fg + 16 * v;
        if (v < 7 && ftile < 104 && (t < TT || ftile < 8)) {
            const bool isEst = ftile < 8;
            const int f0 = (isEst ? ftile : (ftile - 8)) * 16;
            const u16* Bw = (isEst ? WbOut : WbHH0) + (size_t)(f0 + m_) * DH;
            f32x4 acc = {0.f, 0.f, 0.f, 0.f};
            #pragma unroll 4
            for (int kb = 0; kb < DH; kb += 32) {
                short8 a  = *(const short8*)(Atile + m_ * 520 + kb + q8);
                short8 b8 = *(const short8*)(Bw + kb + q8);
                acc = __builtin_amdgcn_mfma_f32_16x16x32_bf16(a, b8, acc, 0, 0, 0);
            }
            if (isEst) {
                const int f = f0 + m_;
                const float bo = bout[f];
                #pragma unroll
                for (int r = 0; r < 4; ++r) {
                    const int b = rowB + r;
                    const float est = acc[r] + bo;
                    if (t < TT) {
                        const int xi = (b * TT + t) * DIN + f;
                        const float x = X[xi], mm = Mm[xi];
                        const float imp = mm * x + (1.f - mm) * est;
                        st_u16_sc(&IMPbf[b * DIN + f], (unsigned)f2bf(imp));
                        pre[xi] = est;
                        if (t > 0) outc[(b * TT + t - 1) * DIN + f] = imp;
                    } else {
                        outc[(b * TT + TT - 1) * DIN + f] = est;   // final est
                    }
                }
            } else {
                const int fp = f0 + m_;                  // 0..1535
                const int g = fp >> 9, ff = fp & 511;
                const float bh = bhh0[fp];
                float* dst = GH0 + (size_t)g * BB * DH + ff;
                #pragma unroll
                for (int r = 0; r < 4; ++r)
                    st_f32_sc(&dst[(size_t)(rowB + r) * DH], acc[r] + bh);
            }
        }
        if (t == TT) break;              // uniform exit
        group_bar(bar, (++ep) * 16);

        // ---------------- stage 2: A = IMP (16 x 128) -------------------
        {
            const u16* src = IMPbf + bb * 16 * DIN;
            for (int ch = tid; ch < 512; ch += 512) {
                const int r = ch >> 5, c = ch & 31;
                *(u64*)(Atile + r * 136 + c * 4) = ld_u64_sc(src + r * DIN + c * 4);
            }
        }
        __syncthreads();

        if (v < 2) {
            const int ff0 = (fg + 16 * v) * 16;
            const int ff = ff0 + m_;
            // hoist GH0 MALL reads above the MFMA loop to hide latency
            float ghr[4], ghz[4], ghn[4];
            #pragma unroll
            for (int r = 0; r < 4; ++r) {
                const int b = rowB + r;
                ghr[r] = ld_f32_sc(&GH0[(size_t)b * DH + ff]);
                ghz[r] = ld_f32_sc(&GH0[((size_t)BB + b) * DH + ff]);
                ghn[r] = ld_f32_sc(&GH0[((size_t)2 * BB + b) * DH + ff]);
            }
            const u16* B0 = WbIH0 + (size_t)(ff0 + m_) * DIN;
            const u16* B1 = B0 + (size_t)DH * DIN;
            const u16* B2 = B1 + (size_t)DH * DIN;
            f32x4 a0 = {0.f,0.f,0.f,0.f}, a1 = a0, a2 = a0;
            #pragma unroll
            for (int kb = 0; kb < DIN; kb += 32) {
                short8 a = *(const short8*)(Atile + m_ * 136 + kb + q8);
                a0 = __builtin_amdgcn_mfma_f32_16x16x32_bf16(a, *(const short8*)(B0 + kb + q8), a0, 0, 0, 0);
                a1 = __builtin_amdgcn_mfma_f32_16x16x32_bf16(a, *(const short8*)(B1 + kb + q8), a1, 0, 0, 0);
                a2 = __builtin_amdgcn_mfma_f32_16x16x32_bf16(a, *(const short8*)(B2 + kb + q8), a2, 0, 0, 0);
            }
            const float bi0 = bih0[ff], bi1 = bih0[DH + ff], bi2 = bih0[2 * DH + ff];
            const int lc = v * 16 + m_;
            #pragma unroll
            for (int r = 0; r < 4; ++r) {
                const int b = rowB + r;
                const float rr = sigm(a0[r] + bi0 + ghr[r]);
                const float zz = sigm(a1[r] + bi1 + ghz[r]);
                const float nn = tanh_f(a2[r] + bi2 + rr * ghn[r]);
                const float hp = H32L[lrow + r][lc];
                const float h1 = (1.f - zz) * nn + zz * hp;
                H132L[lrow + r][lc] = h1;
                st_u16_sc(&H1bf[b * DH + ff], (unsigned)f2bf(h1));
            }
        }
        group_bar(bar, (++ep) * 16);

        // ---------------- stage 3: A = H1 (16 x 512) --------------------
        {
            const u16* src = H1bf + bb * 16 * DH;
            for (int ch = tid; ch < 2048; ch += 512) {
                const int r = ch >> 7, c = ch & 127;
                *(u64*)(Atile + r * 520 + c * 4) = ld_u64_sc(src + r * DH + c * 4);
            }
        }
        __syncthreads();

        float sr[4];                                   // gate-r preact (g==0 waves)
        if (v < 6) {
            const int ft = (v < 3) ? 0 : 1;
            const int g  = v - 3 * ft;
            const int ff0 = (fg + 16 * ft) * 16;
            const u16* Bi = WbIH1 + (size_t)(g * DH + ff0 + m_) * DH;
            const u16* Bh = WbHH1 + (size_t)(g * DH + ff0 + m_) * DH;
            f32x4 ai = {0.f,0.f,0.f,0.f}, ah = ai;
            #pragma unroll 4
            for (int kb = 0; kb < DH; kb += 32) {
                short8 a = *(const short8*)(Atile + m_ * 520 + kb + q8);
                ai = __builtin_amdgcn_mfma_f32_16x16x32_bf16(a, *(const short8*)(Bi + kb + q8), ai, 0, 0, 0);
                ah = __builtin_amdgcn_mfma_f32_16x16x32_bf16(a, *(const short8*)(Bh + kb + q8), ah, 0, 0, 0);
            }
            const int gf = g * DH + ff0 + m_;
            const float bi = bih1[gf], bh = bhh1[gf];
            if (g == 0) {
                #pragma unroll
                for (int r = 0; r < 4; ++r) sr[r] = ai[r] + ah[r] + bi + bh;
            } else if (g == 1) {
                #pragma unroll
                for (int r = 0; r < 4; ++r) cplane[ft][0][m_ * 16 + q * 4 + r] = ai[r] + ah[r] + bi + bh;
            } else {
                #pragma unroll
                for (int r = 0; r < 4; ++r) {
                    cplane[ft][1][m_ * 16 + q * 4 + r] = ai[r] + bi;   // in_
                    cplane[ft][2][m_ * 16 + q * 4 + r] = ah[r] + bh;   // hn
                }
            }
        }
        __syncthreads();
        if (v == 0 || v == 3) {
            const int ft = v / 3;
            const int ff = (fg + 16 * ft) * 16 + m_;
            const int lc = ft * 16 + m_;
            #pragma unroll
            for (int r = 0; r < 4; ++r) {
                const int b = rowB + r;
                const int idx = m_ * 16 + q * 4 + r;
                const float rr = sigm(sr[r]);
                const float zz = sigm(cplane[ft][0][idx]);
                const float nn = tanh_f(cplane[ft][1][idx] + rr * cplane[ft][2][idx]);
                const float h1 = H132L[lrow + r][lc];
                const float hn = (1.f - zz) * nn + zz * h1;
                H32L[lrow + r][lc] = hn;
                st_u16_sc(&Hbf[b * DH + ff], (unsigned)f2bf(hn));
                hsc[((size_t)b * TT + t) * DH + ff] = hn;
                if (t == TT - 1) hfin[(size_t)b * DH + ff] = hn;
            }
        }
        group_bar(bar, (++ep) * 16);
    }
}

extern "C" void kernel_launch(void* const* d_in, const int* in_sizes, int n_in,
                              void* d_out, int out_size, void* d_ws, size_t ws_size,
                              hipStream_t stream) {
    const float* X    = (const float*)d_in[0];
    const float* Mm   = (const float*)d_in[1];
    const float* Wih0 = (const float*)d_in[2];
    const float* Whh0 = (const float*)d_in[3];
    const float* bih0 = (const float*)d_in[4];
    const float* bhh0 = (const float*)d_in[5];
    const float* Wih1 = (const float*)d_in[6];
    const float* Whh1 = (const float*)d_in[7];
    const float* bih1 = (const float*)d_in[8];
    const float* bhh1 = (const float*)d_in[9];
    const float* Wout = (const float*)d_in[10];
    const float* bout = (const float*)d_in[11];
    float* out = (float*)d_out;
    float* ws  = (float*)d_ws;

    // zero barrier counters + Hbf (initial hidden state)
    hipMemsetAsync(d_ws, 0, (size_t)(OFF_H1BF) * sizeof(float), stream);

    // weights fp32 -> bf16
    hipLaunchKernelGGL(prep_kernel, dim3(1024), dim3(256), 0, stream,
                       Wout, Whh0, Wih0, Wih1, Whh1, ws);

    // persistent RNN: 256 WGs (<= 256 CUs) x 512 threads, co-resident
    hipLaunchKernelGGL(rnn_kernel, dim3(256), dim3(512), 0, stream,
                       X, Mm, bih0, bhh0, bih1, bhh1, bout, out, ws);
}

// Round 2
// 5242.858 us; speedup vs baseline: 3.2289x; 1.1735x over previous
//
#include <hip/hip_runtime.h>
#include <cstdint>
#include <cstddef>

// ---------------------------------------------------------------------------
// 2-layer GRU imputation RNN, B=256, T=256, D_IN=128, D_H=512.
// R3: two-phase step (was 3). Phase A fuses layer-0 entirely inside each WG:
// est is replicated (tiny K=512 x 128-col GEMM), GH0 tiles re-mapped so each
// WG computes exactly the 96 GH0 columns it consumes -> GH0/IMP live in LDS,
// stage1->stage2 barrier and their global round-trips are gone.
// fg = blockIdx&15 so XCD(=blockIdx%8) hosts only 2 fg weight slices
// (~0.77 MB incl shared WOUT) -> weights permanently L2-resident (R2 showed
// ~2.7 GB/dispatch of weight L2-thrash with the old bb-major encoding).
// ---------------------------------------------------------------------------

#define BB  256
#define TT  256
#define DIN 128
#define DH  512

typedef __attribute__((ext_vector_type(8))) short short8;   // 8 x bf16
typedef __attribute__((ext_vector_type(4))) float f32x4;
typedef unsigned short u16;
typedef unsigned long long u64;

// ws layout (float units)
#define OFF_BAR   0                               // [16] group counters, 64B apart
#define OFF_HBF   256                             // [256][512] bf16 (carried h)
#define OFF_H1BF  (OFF_HBF + BB*DH/2)             // [256][512] bf16 (layer-0 out)
#define OFF_WOUT  (OFF_H1BF + BB*DH/2)            // bf16 weights below
#define OFF_WHH0  (OFF_WOUT + (DIN*DH)/2)
#define OFF_WIH0  (OFF_WHH0 + (3*DH*DH)/2)
#define OFF_WIH1  (OFF_WIH0 + (3*DH*DIN)/2)
#define OFF_WHH1  (OFF_WIH1 + (3*DH*DH)/2)
#define WS_FLOATS (OFF_WHH1 + (3*DH*DH)/2)

__device__ __forceinline__ float sigm(float x)   { return 1.0f / (1.0f + __expf(-x)); }
__device__ __forceinline__ float tanh_f(float x) { return 2.0f / (1.0f + __expf(-2.0f * x)) - 1.0f; }

__device__ __forceinline__ u16 f2bf(float x) {            // RNE f32->bf16
    unsigned u = __builtin_bit_cast(unsigned, x);
    u += 0x7fffu + ((u >> 16) & 1u);
    return (u16)(u >> 16);
}

// ---- MALL-coherent staged accesses (bypass L1+L2, XCD-agnostic) ------------
__device__ __forceinline__ u64 ld_u64_sc(const u16* p) {
    return __hip_atomic_load((const u64*)p, __ATOMIC_RELAXED, __HIP_MEMORY_SCOPE_AGENT);
}
__device__ __forceinline__ void st_u16_sc(u16* p, unsigned v) {
    // raw sc0 sc1 store: write-through to MALL; avoids 16-bit atomic CAS
    asm volatile("global_store_short %0, %1, off sc0 sc1" :: "v"(p), "v"(v) : "memory");
}

// 16-WG group barrier. Release: drain own stores (sc1 = write-through, so
// vmcnt(0) == visible at MALL). Acquire: consumers read with sc1.
__device__ __forceinline__ void group_bar(unsigned* bar, unsigned target) {
    asm volatile("s_waitcnt vmcnt(0)" ::: "memory");
    __syncthreads();
    if (threadIdx.x == 0) {
        __hip_atomic_fetch_add(bar, 1u, __ATOMIC_RELAXED, __HIP_MEMORY_SCOPE_AGENT);
        while (__hip_atomic_load(bar, __ATOMIC_RELAXED, __HIP_MEMORY_SCOPE_AGENT) < target) {
            __builtin_amdgcn_s_sleep(1);
        }
    }
    __syncthreads();
}

// fp32 -> bf16 weight conversion (runs once per call, before the RNN kernel)
__global__ void prep_kernel(const float* __restrict__ Wout, const float* __restrict__ Whh0,
                            const float* __restrict__ Wih0, const float* __restrict__ Wih1,
                            const float* __restrict__ Whh1, float* __restrict__ ws) {
    u16* dOut = (u16*)(ws + OFF_WOUT);
    u16* dHH0 = (u16*)(ws + OFF_WHH0);
    u16* dIH0 = (u16*)(ws + OFF_WIH0);
    u16* dIH1 = (u16*)(ws + OFF_WIH1);
    u16* dHH1 = (u16*)(ws + OFF_WHH1);
    const int N0 = DIN * DH, N1 = 3 * DH * DH, N2 = 3 * DH * DIN;
    const int total = N0 + 3 * N1 + N2;
    for (int i = blockIdx.x * 256 + threadIdx.x; i < total; i += gridDim.x * 256) {
        int j = i;
        if (j < N0) { dOut[j] = f2bf(Wout[j]); continue; } j -= N0;
        if (j < N1) { dHH0[j] = f2bf(Whh0[j]); continue; } j -= N1;
        if (j < N2) { dIH0[j] = f2bf(Wih0[j]); continue; } j -= N2;
        if (j < N1) { dIH1[j] = f2bf(Wih1[j]); continue; } j -= N1;
        dHH1[j] = f2bf(Whh1[j]);
    }
}

__global__ __launch_bounds__(512) void rnn_kernel(
    const float* __restrict__ X,    const float* __restrict__ Mm,
    const float* __restrict__ bih0, const float* __restrict__ bhh0,
    const float* __restrict__ bih1, const float* __restrict__ bhh1,
    const float* __restrict__ bout,
    float* __restrict__ out, float* __restrict__ ws)
{
    __shared__ __align__(16) u16 Atile[16 * 520];    // H / H1 A-tile (16x512, padded)
    __shared__ __align__(16) u16 IMPL[16 * 136];     // imputed A-tile (16x128, padded)
    __shared__ float ghL[3][2][16][17];              // gh gate preacts (own cols)
    __shared__ float cplane[2][3][256];              // phase-B combine exchange
    __shared__ float H32L[16][33];                   // carried h fp32 (own cols)
    __shared__ float H132L[16][33];                  // layer-0 out fp32 (own cols)

    u16*   Hbf  = (u16*)(ws + OFF_HBF);
    u16*   H1bf = (u16*)(ws + OFF_H1BF);
    const u16* WbOut = (const u16*)(ws + OFF_WOUT);
    const u16* WbHH0 = (const u16*)(ws + OFF_WHH0);
    const u16* WbIH0 = (const u16*)(ws + OFF_WIH0);
    const u16* WbIH1 = (const u16*)(ws + OFF_WIH1);
    const u16* WbHH1 = (const u16*)(ws + OFF_WHH1);

    float* pre  = out;                               // [B][T][DIN]
    float* outc = out + BB * TT * DIN;               // [B][T][DIN]
    float* hfin = out + 2 * BB * TT * DIN;           // [B][DH]
    float* hsc  = hfin + BB * DH;                    // [B][T][DH]

    const int tid  = threadIdx.x;
    const int lane = tid & 63;
    const int v    = tid >> 6;           // wave 0..7
    const int fg   = blockIdx.x & 15;    // feature group (XCD = fg%8 -> L2 weight locality)
    const int bb   = blockIdx.x >> 4;    // batch block (16 rows) == barrier group
    const int m_   = lane & 15;          // A-row / B-col / C-col index
    const int q    = lane >> 4;          // quad
    const int q8   = q * 8;
    const int rowB = bb * 16 + q * 4;    // C-row batch base (+r)
    const int lrow = q * 4;              // local row base (+r)

    unsigned* bar = (unsigned*)(ws + OFF_BAR) + bb * 16;   // 64B-spaced counter
    unsigned ep = 0;

    // zero carried-h LDS (t==0 initial state)
    ((float*)H32L)[tid] = 0.f;
    if (tid < 16 * 33 - 512) ((float*)H32L)[512 + tid] = 0.f;

    // phase-A wave assignments (constant over t)
    const int fE  = v * 16 + m_;                     // est col (replicated tiles)
    const int g   = v >> 1, ft = v & 1;              // GH0 tile (waves 0..5)
    const int fp  = g * DH + (fg + 16 * ft) * 16 + m_;  // GH0 col

    for (int t = 0; t <= TT; ++t) {
        // ------------- phase A: est + GH0 + layer-0 gates + H1 -------------
        float xv[4], mv[4];
        if (t < TT) {                                // prefetch X/Mm (plain, cached)
            #pragma unroll
            for (int r = 0; r < 4; ++r) {
                const int xi = ((rowB + r) * TT + t) * DIN + fE;
                xv[r] = X[xi]; mv[r] = Mm[xi];
            }
        }
        {   // stage Hbf -> Atile (MALL-coherent)
            const u16* src = Hbf + bb * 16 * DH;
            for (int ch = tid; ch < 2048; ch += 512) {
                const int r = ch >> 7, c = ch & 127;
                *(u64*)(Atile + r * 520 + c * 4) = ld_u64_sc(src + r * DH + c * 4);
            }
        }
        __syncthreads();

        const u16* BwE = WbOut + (size_t)fE * DH;
        const u16* BwG = WbHH0 + (size_t)fp * DH;
        f32x4 aE = {0.f, 0.f, 0.f, 0.f}, aG = aE;
        if (v < 6) {
            #pragma unroll 4
            for (int kb = 0; kb < DH; kb += 32) {
                short8 a = *(const short8*)(Atile + m_ * 520 + kb + q8);
                aE = __builtin_amdgcn_mfma_f32_16x16x32_bf16(a, *(const short8*)(BwE + kb + q8), aE, 0, 0, 0);
                aG = __builtin_amdgcn_mfma_f32_16x16x32_bf16(a, *(const short8*)(BwG + kb + q8), aG, 0, 0, 0);
            }
        } else {
            #pragma unroll 4
            for (int kb = 0; kb < DH; kb += 32) {
                short8 a = *(const short8*)(Atile + m_ * 520 + kb + q8);
                aE = __builtin_amdgcn_mfma_f32_16x16x32_bf16(a, *(const short8*)(BwE + kb + q8), aE, 0, 0, 0);
            }
        }

        const float bo = bout[fE];
        if (t == TT) {                               // tail: only final est
            if (v == fg) {
                #pragma unroll
                for (int r = 0; r < 4; ++r)
                    outc[((rowB + r) * TT + TT - 1) * DIN + fE] = aE[r] + bo;
            }
            break;                                   // uniform exit
        }
        #pragma unroll
        for (int r = 0; r < 4; ++r) {
            const float est = aE[r] + bo;
            const float imp = mv[r] * xv[r] + (1.f - mv[r]) * est;
            IMPL[(lrow + r) * 136 + fE] = f2bf(imp);
            if (v == fg) {                           // one WG per group stores tile fg
                const int xi = ((rowB + r) * TT + t) * DIN + fE;
                pre[xi] = est;
                if (t > 0) outc[xi - DIN] = imp;
            }
        }
        if (v < 6) {
            const float bh = bhh0[fp];
            #pragma unroll
            for (int r = 0; r < 4; ++r) ghL[g][ft][lrow + r][m_] = aG[r] + bh;
        }
        __syncthreads();

        if (v < 2) {                                 // layer-0 gates + combine
            const int ff0 = (fg + 16 * v) * 16;
            const int ff  = ff0 + m_;
            const u16* B0 = WbIH0 + (size_t)ff * DIN;
            const u16* B1 = B0 + (size_t)DH * DIN;
            const u16* B2 = B1 + (size_t)DH * DIN;
            f32x4 a0 = {0.f,0.f,0.f,0.f}, a1 = a0, a2 = a0;
            #pragma unroll
            for (int kb = 0; kb < DIN; kb += 32) {
                short8 a = *(const short8*)(IMPL + m_ * 136 + kb + q8);
                a0 = __builtin_amdgcn_mfma_f32_16x16x32_bf16(a, *(const short8*)(B0 + kb + q8), a0, 0, 0, 0);
                a1 = __builtin_amdgcn_mfma_f32_16x16x32_bf16(a, *(const short8*)(B1 + kb + q8), a1, 0, 0, 0);
                a2 = __builtin_amdgcn_mfma_f32_16x16x32_bf16(a, *(const short8*)(B2 + kb + q8), a2, 0, 0, 0);
            }
            const float bi0 = bih0[ff], bi1 = bih0[DH + ff], bi2 = bih0[2 * DH + ff];
            const int lc = v * 16 + m_;
            #pragma unroll
            for (int r = 0; r < 4; ++r) {
                const float rr = sigm(a0[r] + bi0 + ghL[0][v][lrow + r][m_]);
                const float zz = sigm(a1[r] + bi1 + ghL[1][v][lrow + r][m_]);
                const float nn = tanh_f(a2[r] + bi2 + rr * ghL[2][v][lrow + r][m_]);
                const float hp = H32L[lrow + r][lc];
                const float h1 = (1.f - zz) * nn + zz * hp;
                H132L[lrow + r][lc] = h1;
                st_u16_sc(&H1bf[(rowB + r) * DH + ff], (unsigned)f2bf(h1));
            }
        }
        group_bar(bar, (++ep) * 16);

        // ------------- phase B: layer-1 (A = H1, 16 x 512) -------------
        {
            const u16* src = H1bf + bb * 16 * DH;
            for (int ch = tid; ch < 2048; ch += 512) {
                const int r = ch >> 7, c = ch & 127;
                *(u64*)(Atile + r * 520 + c * 4) = ld_u64_sc(src + r * DH + c * 4);
            }
        }
        __syncthreads();

        float sr[4];                                   // gate-r preact (g==0 waves)
        if (v < 6) {
            const int ft3 = (v < 3) ? 0 : 1;
            const int g3  = v - 3 * ft3;
            const int ff0 = (fg + 16 * ft3) * 16;
            const u16* Bi = WbIH1 + (size_t)(g3 * DH + ff0 + m_) * DH;
            const u16* Bh = WbHH1 + (size_t)(g3 * DH + ff0 + m_) * DH;
            f32x4 ai = {0.f,0.f,0.f,0.f}, ah = ai;
            #pragma unroll 4
            for (int kb = 0; kb < DH; kb += 32) {
                short8 a = *(const short8*)(Atile + m_ * 520 + kb + q8);
                ai = __builtin_amdgcn_mfma_f32_16x16x32_bf16(a, *(const short8*)(Bi + kb + q8), ai, 0, 0, 0);
                ah = __builtin_amdgcn_mfma_f32_16x16x32_bf16(a, *(const short8*)(Bh + kb + q8), ah, 0, 0, 0);
            }
            const int gf = g3 * DH + ff0 + m_;
            const float bi = bih1[gf], bh = bhh1[gf];
            if (g3 == 0) {
                #pragma unroll
                for (int r = 0; r < 4; ++r) sr[r] = ai[r] + ah[r] + bi + bh;
            } else if (g3 == 1) {
                #pragma unroll
                for (int r = 0; r < 4; ++r) cplane[ft3][0][m_ * 16 + q * 4 + r] = ai[r] + ah[r] + bi + bh;
            } else {
                #pragma unroll
                for (int r = 0; r < 4; ++r) {
                    cplane[ft3][1][m_ * 16 + q * 4 + r] = ai[r] + bi;   // in_
                    cplane[ft3][2][m_ * 16 + q * 4 + r] = ah[r] + bh;   // hn
                }
            }
        }
        __syncthreads();
        if (v == 0 || v == 3) {
            const int ft3 = v / 3;
            const int ff = (fg + 16 * ft3) * 16 + m_;
            const int lc = ft3 * 16 + m_;
            #pragma unroll
            for (int r = 0; r < 4; ++r) {
                const int b = rowB + r;
                const int idx = m_ * 16 + q * 4 + r;
                const float rr = sigm(sr[r]);
                const float zz = sigm(cplane[ft3][0][idx]);
                const float nn = tanh_f(cplane[ft3][1][idx] + rr * cplane[ft3][2][idx]);
                const float h1 = H132L[lrow + r][lc];
                const float hn = (1.f - zz) * nn + zz * h1;
                H32L[lrow + r][lc] = hn;
                st_u16_sc(&Hbf[b * DH + ff], (unsigned)f2bf(hn));
                hsc[((size_t)b * TT + t) * DH + ff] = hn;
                if (t == TT - 1) hfin[(size_t)b * DH + ff] = hn;
            }
        }
        group_bar(bar, (++ep) * 16);
    }
}

extern "C" void kernel_launch(void* const* d_in, const int* in_sizes, int n_in,
                              void* d_out, int out_size, void* d_ws, size_t ws_size,
                              hipStream_t stream) {
    const float* X    = (const float*)d_in[0];
    const float* Mm   = (const float*)d_in[1];
    const float* Wih0 = (const float*)d_in[2];
    const float* Whh0 = (const float*)d_in[3];
    const float* bih0 = (const float*)d_in[4];
    const float* bhh0 = (const float*)d_in[5];
    const float* Wih1 = (const float*)d_in[6];
    const float* Whh1 = (const float*)d_in[7];
    const float* bih1 = (const float*)d_in[8];
    const float* bhh1 = (const float*)d_in[9];
    const float* Wout = (const float*)d_in[10];
    const float* bout = (const float*)d_in[11];
    float* out = (float*)d_out;
    float* ws  = (float*)d_ws;

    // zero barrier counters + Hbf (initial hidden state)
    hipMemsetAsync(d_ws, 0, (size_t)(OFF_H1BF) * sizeof(float), stream);

    // weights fp32 -> bf16
    hipLaunchKernelGGL(prep_kernel, dim3(1024), dim3(256), 0, stream,
                       Wout, Whh0, Wih0, Wih1, Whh1, ws);

    // persistent RNN: 256 WGs (<= 256 CUs) x 512 threads, co-resident
    hipLaunchKernelGGL(rnn_kernel, dim3(256), dim3(512), 0, stream,
                       X, Mm, bih0, bhh0, bih1, bhh1, bout, out, ws);
}